// Round 1
// baseline (123.426 us; speedup 1.0000x reference)
//
#include <hip/hip_runtime.h>
#include <math.h>

// Problem constants (from reference setup_inputs)
constexpr int B = 64, Q = 900, C = 256, T = 200;
constexpr float BIG = 1000000.0f;
constexpr float EPSV = 1e-6f;
constexpr int WAVES_PER_BLOCK = 4;           // one q-row per wave
constexpr int QPB = WAVES_PER_BLOCK;         // q rows per block

// nan/posinf/neginf -> 0 (for logits: nan_to_num(nan=0, posinf=0, neginf=0))
__device__ __forceinline__ float fix_logit(float x) {
    unsigned u = __float_as_uint(x);
    return ((u & 0x7f800000u) == 0x7f800000u) ? 0.0f : x;
}

// boxes: nan -> 0, +inf -> 1, -inf -> 0
__device__ __forceinline__ float fix_box(float x) {
    unsigned u = __float_as_uint(x);
    if ((u & 0x7f800000u) == 0x7f800000u) {
        if (u & 0x007fffffu) return 0.0f;            // NaN
        return (u & 0x80000000u) ? 0.0f : 1.0f;      // -inf : +inf
    }
    return x;
}

__device__ __forceinline__ float clampf(float x, float lo, float hi) {
    return fminf(fmaxf(x, lo), hi);
}

__global__ __launch_bounds__(256, 2)
void matcher_kernel(const float* __restrict__ logits,   // [B,Q,C]
                    const float* __restrict__ pboxes,   // [B,Q,4] cxcywh
                    const int*   __restrict__ tlabels,  // [B,T]
                    const float* __restrict__ tboxes,   // [B,T,4] cxcywh
                    float* __restrict__ out)            // [B,Q,T]
{
    __shared__ float s_tx0[T], s_ty0[T], s_tx1[T], s_ty1[T], s_tarea[T];
    __shared__ float s_tcx[T], s_tcy[T], s_tw[T], s_th[T];
    __shared__ int   s_tlab[T];
    __shared__ float s_exp[WAVES_PER_BLOCK][C];

    const int blocks_per_b = Q / QPB;                 // 225
    const int b    = blockIdx.x / blocks_per_b;
    const int qblk = blockIdx.x % blocks_per_b;
    const int tid  = threadIdx.x;
    const int wave = tid >> 6;
    const int lane = tid & 63;
    const int q    = qblk * QPB + wave;

    // ---- stage sanitized targets for this batch into LDS (shared by 4 waves)
    for (int t = tid; t < T; t += blockDim.x) {
        float4 tb = ((const float4*)(tboxes + (size_t)b * T * 4))[t];
        float cx = clampf(fix_box(tb.x), 0.0f, 1.0f);
        float cy = clampf(fix_box(tb.y), 0.0f, 1.0f);
        float w  = clampf(fix_box(tb.z), EPSV, 1.0f);
        float h  = clampf(fix_box(tb.w), EPSV, 1.0f);
        s_tcx[t] = cx; s_tcy[t] = cy; s_tw[t] = w; s_th[t] = h;
        float x0 = cx - 0.5f * w, y0 = cy - 0.5f * h;
        float x1 = cx + 0.5f * w, y1 = cy + 0.5f * h;
        s_tx0[t] = x0; s_ty0[t] = y0; s_tx1[t] = x1; s_ty1[t] = y1;
        s_tarea[t] = (x1 - x0) * (y1 - y0);
        int lab = tlabels[(size_t)b * T + t];
        s_tlab[t] = min(max(lab, 0), C - 1);
    }

    // ---- per-wave softmax over the 256 logits of row (b,q)
    const size_t row = (size_t)b * Q + q;
    const float4 lg4 = ((const float4*)(logits + row * C))[lane];
    float l0 = fix_logit(lg4.x), l1 = fix_logit(lg4.y);
    float l2 = fix_logit(lg4.z), l3 = fix_logit(lg4.w);

    float m = fmaxf(fmaxf(l0, l1), fmaxf(l2, l3));
    #pragma unroll
    for (int off = 32; off > 0; off >>= 1)
        m = fmaxf(m, __shfl_xor(m, off));

    float e0 = __expf(l0 - m), e1 = __expf(l1 - m);
    float e2 = __expf(l2 - m), e3 = __expf(l3 - m);
    float s = (e0 + e1) + (e2 + e3);
    #pragma unroll
    for (int off = 32; off > 0; off >>= 1)
        s += __shfl_xor(s, off);
    const float inv_sum = 1.0f / s;

    ((float4*)&s_exp[wave][0])[lane] = make_float4(e0, e1, e2, e3);

    // ---- sanitized pred box for this row (uniform across the wave)
    const float4 pb = *(const float4*)(pboxes + row * 4);
    float pcx = clampf(fix_box(pb.x), 0.0f, 1.0f);
    float pcy = clampf(fix_box(pb.y), 0.0f, 1.0f);
    float pw  = clampf(fix_box(pb.z), EPSV, 1.0f);
    float ph  = clampf(fix_box(pb.w), EPSV, 1.0f);
    float px0 = pcx - 0.5f * pw, py0 = pcy - 0.5f * ph;
    float px1 = pcx + 0.5f * pw, py1 = pcy + 0.5f * ph;
    float parea = (px1 - px0) * (py1 - py0);

    __syncthreads();

    // ---- pairwise costs: lane covers t = lane, lane+64, ... (coalesced stores)
    float* orow = out + row * T;
    for (int t = lane; t < T; t += 64) {
        float prob = s_exp[wave][s_tlab[t]] * inv_sum;

        float l1c = fabsf(pcx - s_tcx[t]) + fabsf(pcy - s_tcy[t])
                  + fabsf(pw  - s_tw[t])  + fabsf(ph  - s_th[t]);

        float ltx = fmaxf(px0, s_tx0[t]), lty = fmaxf(py0, s_ty0[t]);
        float rbx = fminf(px1, s_tx1[t]), rby = fminf(py1, s_ty1[t]);
        float iw = fmaxf(rbx - ltx, 0.0f), ih = fmaxf(rby - lty, 0.0f);
        float inter = iw * ih;
        float uni = parea + s_tarea[t] - inter;
        float iou = inter / uni;

        float cx0 = fminf(px0, s_tx0[t]), cy0 = fminf(py0, s_ty0[t]);
        float cx1 = fmaxf(px1, s_tx1[t]), cy1 = fmaxf(py1, s_ty1[t]);
        float cw = fmaxf(cx1 - cx0, 0.0f), ch = fmaxf(cy1 - cy0, 0.0f);
        float ca = cw * ch;
        float giou = iou - (ca - uni) / ca;

        float cost = -prob + 5.0f * l1c - 2.0f * giou;
        // nan_to_num(nan=BIG, posinf=BIG, neginf=BIG)
        unsigned cu = __float_as_uint(cost);
        if ((cu & 0x7f800000u) == 0x7f800000u) cost = BIG;
        orow[t] = cost;
    }
}

extern "C" void kernel_launch(void* const* d_in, const int* in_sizes, int n_in,
                              void* d_out, int out_size, void* d_ws, size_t ws_size,
                              hipStream_t stream) {
    const float* logits  = (const float*)d_in[0];
    const float* pboxes  = (const float*)d_in[1];
    const int*   tlabels = (const int*)d_in[2];
    const float* tboxes  = (const float*)d_in[3];
    float* out = (float*)d_out;

    dim3 grid(B * (Q / QPB));   // 64 * 225 = 14400 blocks
    dim3 block(64 * WAVES_PER_BLOCK);
    matcher_kernel<<<grid, block, 0, stream>>>(logits, pboxes, tlabels, tboxes, out);
}

// Round 2
// 121.149 us; speedup vs baseline: 1.0188x; 1.0188x over previous
//
#include <hip/hip_runtime.h>
#include <math.h>

// Problem constants (from reference setup_inputs)
constexpr int B = 64, Q = 900, C = 256, T = 200;
constexpr float EPSV = 1e-6f;
constexpr int WPB = 4;              // waves per block
constexpr int QPW = 8;              // q rows per wave
constexpr int QPB = WPB * QPW;      // 32 q rows per block

// nan/±inf -> 0 (logits: nan_to_num(nan=0, posinf=0, neginf=0))
__device__ __forceinline__ float fix_logit(float x) {
    unsigned u = __float_as_uint(x);
    return ((u & 0x7f800000u) == 0x7f800000u) ? 0.0f : x;
}

// boxes: nan -> 0, +inf -> 1, -inf -> 0
__device__ __forceinline__ float fix_box(float x) {
    unsigned u = __float_as_uint(x);
    if ((u & 0x7f800000u) == 0x7f800000u) {
        if (u & 0x007fffffu) return 0.0f;            // NaN
        return (u & 0x80000000u) ? 0.0f : 1.0f;      // -inf : +inf
    }
    return x;
}

__device__ __forceinline__ float clampf(float x, float lo, float hi) {
    return fminf(fmaxf(x, lo), hi);
}

__global__ __launch_bounds__(256, 4)
void matcher_kernel(const float* __restrict__ logits,   // [B,Q,C]
                    const float* __restrict__ pboxes,   // [B,Q,4] cxcywh
                    const int*   __restrict__ tlabels,  // [B,T]
                    const float* __restrict__ tboxes,   // [B,T,4] cxcywh
                    float* __restrict__ out)            // [B,Q,T]
{
    // one exp-row per wave; no cross-wave sharing -> no __syncthreads anywhere
    __shared__ float s_exp[WPB * C];

    const int blocks_per_b = (Q + QPB - 1) / QPB;     // 29
    const int b    = blockIdx.x / blocks_per_b;
    const int qblk = blockIdx.x % blocks_per_b;
    const int wave = threadIdx.x >> 6;
    const int lane = threadIdx.x & 63;
    const int q0   = qblk * QPB + wave * QPW;

    // ---- per-lane target registers: slot s covers t = lane + 64*s
    // (loaded once per block; slot 3 valid only for lanes < 8)
    float tx0[4], ty0[4], tx1[4], ty1[4], tw[4], th[4];
    int   lofs[4];
    #pragma unroll
    for (int s = 0; s < 4; ++s) {
        int t  = lane + 64 * s;
        int tc = t < T ? t : T - 1;                   // clamp for safe load
        float4 tb = ((const float4*)(tboxes + (size_t)b * T * 4))[tc];
        float cx = clampf(fix_box(tb.x), 0.0f, 1.0f);
        float cy = clampf(fix_box(tb.y), 0.0f, 1.0f);
        float w  = clampf(fix_box(tb.z), EPSV, 1.0f);
        float h  = clampf(fix_box(tb.w), EPSV, 1.0f);
        tw[s] = w;  th[s] = h;
        tx0[s] = cx - 0.5f * w;  ty0[s] = cy - 0.5f * h;
        tx1[s] = cx + 0.5f * w;  ty1[s] = cy + 0.5f * h;
        int lab = tlabels[(size_t)b * T + tc];
        lofs[s] = wave * C + min(max(lab, 0), C - 1); // loop-invariant gather idx
    }

    for (int i = 0; i < QPW; ++i) {
        const int q = q0 + i;
        if (q >= Q) break;                            // wave-uniform
        const size_t row = (size_t)b * Q + q;

        // ---- softmax over this row's 256 logits (one wave, float4/lane)
        float4 lg = ((const float4*)(logits + row * C))[lane];
        float l0 = fix_logit(lg.x), l1 = fix_logit(lg.y);
        float l2 = fix_logit(lg.z), l3 = fix_logit(lg.w);
        float m = fmaxf(fmaxf(l0, l1), fmaxf(l2, l3));
        #pragma unroll
        for (int off = 32; off; off >>= 1) m = fmaxf(m, __shfl_xor(m, off));
        float e0 = __expf(l0 - m), e1 = __expf(l1 - m);
        float e2 = __expf(l2 - m), e3 = __expf(l3 - m);
        float ssum = (e0 + e1) + (e2 + e3);
        #pragma unroll
        for (int off = 32; off; off >>= 1) ssum += __shfl_xor(ssum, off);
        const float inv = __builtin_amdgcn_rcpf(ssum);
        ((float4*)(s_exp + wave * C))[lane] = make_float4(e0, e1, e2, e3);

        // ---- sanitized pred box (wave-uniform values)
        float4 pb = *(const float4*)(pboxes + row * 4);
        float pcx = clampf(fix_box(pb.x), 0.0f, 1.0f);
        float pcy = clampf(fix_box(pb.y), 0.0f, 1.0f);
        float pw  = clampf(fix_box(pb.z), EPSV, 1.0f);
        float ph  = clampf(fix_box(pb.w), EPSV, 1.0f);
        float px0 = pcx - 0.5f * pw, py0 = pcy - 0.5f * ph;
        float px1 = pcx + 0.5f * pw, py1 = pcy + 0.5f * ph;
        float psx = px0 + px1, psy = py0 + py1;       // 2*pcx, 2*pcy
        float parea = pw * ph;

        float* orow = out + row * T;
        #pragma unroll
        for (int s = 0; s < 4; ++s) {
            // cost_class folded with the "+2" from giou's (val-1) rewrite:
            // t0 = 2 - prob
            float g  = s_exp[lofs[s]];
            float t0 = fmaf(-g, inv, 2.0f);

            // 5 * L1  =  2.5*(|psx-tsx| + |psy-tsy|) + 5*(|pw-tw| + |ph-th|)
            float tsx = tx0[s] + tx1[s];
            float tsy = ty0[s] + ty1[s];
            float s1 = fabsf(psx - tsx) + fabsf(psy - tsy);
            float s2 = fabsf(pw - tw[s]) + fabsf(ph - th[s]);

            // intersection / union
            float iw = fminf(px1, tx1[s]) - fmaxf(px0, tx0[s]);
            float ih = fminf(py1, ty1[s]) - fmaxf(py0, ty0[s]);
            iw = fmaxf(iw, 0.0f);  ih = fmaxf(ih, 0.0f);
            float inter = iw * ih;
            float uni = fmaf(tw[s], th[s], parea) - inter;

            // enclosing box (always non-degenerate: w,h >= eps)
            float cw = fmaxf(px1, tx1[s]) - fminf(px0, tx0[s]);
            float ch = fmaxf(py1, ty1[s]) - fminf(py0, ty0[s]);
            float ca = cw * ch;

            // giou = iou - (ca-uni)/ca = val - 1,
            // val = inter/uni + uni/ca = (inter*ca + uni^2) / (uni*ca)
            float num = fmaf(uni, uni, inter * ca);
            float val = num * __builtin_amdgcn_rcpf(uni * ca);

            // cost = (2 - prob) + 2.5*s1 + 5*s2 - 2*val   (provably finite)
            float cost = fmaf(2.5f, s1, t0);
            cost = fmaf(5.0f, s2, cost);
            cost = fmaf(-2.0f, val, cost);

            int t = lane + 64 * s;
            if (t < T) orow[t] = cost;
        }
    }
}

extern "C" void kernel_launch(void* const* d_in, const int* in_sizes, int n_in,
                              void* d_out, int out_size, void* d_ws, size_t ws_size,
                              hipStream_t stream) {
    const float* logits  = (const float*)d_in[0];
    const float* pboxes  = (const float*)d_in[1];
    const int*   tlabels = (const int*)d_in[2];
    const float* tboxes  = (const float*)d_in[3];
    float* out = (float*)d_out;

    const int blocks_per_b = (Q + QPB - 1) / QPB;     // 29
    dim3 grid(B * blocks_per_b);                      // 1856 blocks
    dim3 block(64 * WPB);                             // 256 threads
    matcher_kernel<<<grid, block, 0, stream>>>(logits, pboxes, tlabels, tboxes, out);
}